// Round 1
// baseline (2861.336 us; speedup 1.0000x reference)
//
#include <hip/hip_runtime.h>
#include <cstddef>
#include <cstdint>

#define EPS_F 1e-7f
#define MAX_NORM_F 0.99999f   // (1 - 1e-5) / SC, SC = 1

// ---------------------------------------------------------------- reductions
__device__ __forceinline__ float wave_sum(float v) {
#pragma unroll
  for (int off = 32; off; off >>= 1) v += __shfl_xor(v, off);
  return v;
}

__device__ __forceinline__ float block_sum(float v, float* red) {
  const int lane = threadIdx.x & 63;
  const int w = threadIdx.x >> 6;
  v = wave_sum(v);
  __syncthreads();                 // protect red[] from previous use
  if (lane == 0) red[w] = v;
  __syncthreads();
  return red[0] + red[1] + red[2] + red[3];
}

// ---------------------------------------------------------------- fp32 GEMM
// C[M,N] = A[M,K] @ B[K,N] (+bias) (optional relu). Row-major, tight strides.
// 64x64 tile, BK=16, 256 threads, 4x4 microtile.
#define BM 64
#define BN 64
#define BK 16

__global__ __launch_bounds__(256) void gemm_f32(
    const float* __restrict__ A, const float* __restrict__ Bm,
    const float* __restrict__ bias, float* __restrict__ C,
    int M, int N, int K, int relu)
{
  __shared__ float As[BK][BM];   // transposed A tile
  __shared__ float Bs[BK][BN];
  const int bm = blockIdx.x * BM;
  const int bn = blockIdx.y * BN;
  const int t  = threadIdx.x;
  const int cx = t & 15;         // N direction
  const int cy = t >> 4;         // M direction
  const int a_row = t >> 2;          // 0..63
  const int a_kk  = (t & 3) << 2;    // 0,4,8,12
  const int b_kk  = t >> 4;          // 0..15
  const int b_col = (t & 15) << 2;   // 0..60

  float acc[4][4] = {};

  for (int k0 = 0; k0 < K; k0 += BK) {
    {  // A tile: float4 along K, store transposed
      int gr = bm + a_row;
      int gk = k0 + a_kk;
      float4 v = make_float4(0.f, 0.f, 0.f, 0.f);
      if (gr < M && gk < K) {
        if (gk + 3 < K) {
          v = *reinterpret_cast<const float4*>(A + (size_t)gr * K + gk);
        } else {
          const float* p = A + (size_t)gr * K;
          v.x = p[gk];
          if (gk + 1 < K) v.y = p[gk + 1];
          if (gk + 2 < K) v.z = p[gk + 2];
        }
      }
      As[a_kk + 0][a_row] = v.x;
      As[a_kk + 1][a_row] = v.y;
      As[a_kk + 2][a_row] = v.z;
      As[a_kk + 3][a_row] = v.w;
    }
    {  // B tile: float4 along N
      int gk = k0 + b_kk;
      int gc = bn + b_col;
      float4 v = make_float4(0.f, 0.f, 0.f, 0.f);
      if (gk < K) {
        if (gc + 3 < N) {
          v = *reinterpret_cast<const float4*>(Bm + (size_t)gk * N + gc);
        } else {
          const float* p = Bm + (size_t)gk * N;
          if (gc     < N) v.x = p[gc];
          if (gc + 1 < N) v.y = p[gc + 1];
          if (gc + 2 < N) v.z = p[gc + 2];
        }
      }
      *reinterpret_cast<float4*>(&Bs[b_kk][b_col]) = v;
    }
    __syncthreads();
#pragma unroll
    for (int k = 0; k < BK; ++k) {
      float4 a4 = *reinterpret_cast<const float4*>(&As[k][cy << 2]);
      float4 b4 = *reinterpret_cast<const float4*>(&Bs[k][cx << 2]);
      float av[4] = {a4.x, a4.y, a4.z, a4.w};
      float bv[4] = {b4.x, b4.y, b4.z, b4.w};
#pragma unroll
      for (int i = 0; i < 4; ++i)
#pragma unroll
        for (int j = 0; j < 4; ++j)
          acc[i][j] = fmaf(av[i], bv[j], acc[i][j]);
    }
    __syncthreads();
  }

#pragma unroll
  for (int i = 0; i < 4; ++i) {
    int gr = bm + (cy << 2) + i;
    if (gr >= M) continue;
#pragma unroll
    for (int j = 0; j < 4; ++j) {
      int gc = bn + (cx << 2) + j;
      if (gc >= N) continue;
      float v = acc[i][j];
      if (bias) v += bias[gc];
      if (relu) v = fmaxf(v, 0.f);
      C[(size_t)gr * N + gc] = v;
    }
  }
}

// ------------------------------------------------- LayerNorm + expmap0 -> Z
// One block (256 thr) per (b, n) row. Writes all 5 groups of z_all into Z.
// Z layout: [5*512 rows][38 cols][256], row = g*512 + b, col n.
__global__ __launch_bounds__(256) void ln_expmap0_k(
    const float* __restrict__ TAN, const float* __restrict__ gamma,
    const float* __restrict__ beta, float* __restrict__ Z)
{
  __shared__ float red[4];
  const int row = blockIdx.x;     // b*30 + n
  const int d = threadIdx.x;
  const int b = row / 30;
  const int n = row % 30;

  float tc[4];
  float tsum = 0.f;
#pragma unroll
  for (int c = 0; c < 4; ++c) {
    float x = TAN[((size_t)c * 15360 + row) * 256 + d];
    float mu = block_sum(x, red) * (1.f / 256.f);
    float xm = x - mu;
    float var = block_sum(xm * xm, red) * (1.f / 256.f);
    float tv = xm * rsqrtf(var + 1e-5f) * gamma[c * 256 + d] + beta[c * 256 + d];
    tc[c] = tv;
    tsum += tv;
  }
#pragma unroll
  for (int g = 0; g < 5; ++g) {
    float v = (g == 0) ? tsum : tc[g - 1];
    float n2 = block_sum(v * v, red);
    float nn = fmaxf(sqrtf(n2), EPS_F);
    float th = tanhf(nn);
    float w = v * (th / nn);
    if (th > MAX_NORM_F) w *= MAX_NORM_F / fmaxf(th, EPS_F);
    Z[(((size_t)g * 512 + b) * 38 + n) * 256 + d] = w;
  }
}

// ---------------------------------------- velocity + feat (per step t)
// One wave per latent row r (2560 rows). feat = [logmap0(z_last),
// logmap0(z_prev), mean_j logmap(zw[j], zw[j+1])].
__global__ __launch_bounds__(256) void vel_feat_k(
    const float* __restrict__ Z, float* __restrict__ FEAT, int t)
{
  const int r = blockIdx.x * 4 + (threadIdx.x >> 6);
  const int lane = threadIdx.x & 63;
  const float* zr = Z + (size_t)r * 38 * 256;

  float4 x = *reinterpret_cast<const float4*>(zr + (size_t)t * 256 + lane * 4);
  float x2 = wave_sum(x.x * x.x + x.y * x.y + x.z * x.z + x.w * x.w);
  float4 vel = make_float4(0.f, 0.f, 0.f, 0.f);
  float4 zprev = x;
  float zprev2 = x2;

  for (int j = 0; j < 29; ++j) {
    float4 y = *reinterpret_cast<const float4*>(zr + (size_t)(t + j + 1) * 256 + lane * 4);
    float y2 = wave_sum(y.x * y.x + y.y * y.y + y.z * y.z + y.w * y.w);
    float xy = wave_sum(x.x * y.x + x.y * y.y + x.z * y.z + x.w * y.w);
    // u = mobius_add(-x, y)
    float a  = 1.f - 2.f * xy + y2;      // coeff on (-x)
    float bb = 1.f - x2;                 // coeff on y
    float den = fmaxf(1.f - 2.f * xy + x2 * y2, EPS_F);
    float inv = 1.f / den;
    float4 u;
    u.x = (bb * y.x - a * x.x) * inv;
    u.y = (bb * y.y - a * x.y) * inv;
    u.z = (bb * y.z - a * x.z) * inv;
    u.w = (bb * y.w - a * x.w) * inv;
    float u2 = wave_sum(u.x * u.x + u.y * u.y + u.z * u.z + u.w * u.w);
    float un = fmaxf(sqrtf(u2), EPS_F);
    // 2/(SC*lam(x)) = max(1 - x2, EPS)
    float coef = fmaxf(1.f - x2, EPS_F) * atanhf(fminf(un, 1.f - 1e-7f)) / un;
    vel.x += coef * u.x; vel.y += coef * u.y;
    vel.z += coef * u.z; vel.w += coef * u.w;
    if (j == 28) { zprev = x; zprev2 = x2; }   // x is col t+28 here
    x = y; x2 = y2;                            // after j=28: x = z_last
  }

  const float s29 = 1.f / 29.f;
  float nl = fmaxf(sqrtf(x2), EPS_F);
  float cl = atanhf(fminf(nl, 1.f - 1e-7f)) / nl;
  float np_ = fmaxf(sqrtf(zprev2), EPS_F);
  float cp = atanhf(fminf(np_, 1.f - 1e-7f)) / np_;

  float* f = FEAT + (size_t)r * 768;
  float4 o;
  o.x = cl * x.x; o.y = cl * x.y; o.z = cl * x.z; o.w = cl * x.w;
  *reinterpret_cast<float4*>(f + lane * 4) = o;
  o.x = cp * zprev.x; o.y = cp * zprev.y; o.z = cp * zprev.z; o.w = cp * zprev.w;
  *reinterpret_cast<float4*>(f + 256 + lane * 4) = o;
  o.x = vel.x * s29; o.y = vel.y * s29; o.z = vel.z * s29; o.w = vel.w * s29;
  *reinterpret_cast<float4*>(f + 512 + lane * 4) = o;
}

// ------------------------------------------------ z_next = expmap(z_last, v)
__global__ __launch_bounds__(256) void expmap_step_k(
    float* __restrict__ Z, const float* __restrict__ V, int t)
{
  const int r = blockIdx.x * 4 + (threadIdx.x >> 6);
  const int lane = threadIdx.x & 63;
  float* zr = Z + (size_t)r * 38 * 256;
  float4 x = *reinterpret_cast<const float4*>(zr + (size_t)(t + 29) * 256 + lane * 4);
  float4 v = *reinterpret_cast<const float4*>(V + (size_t)r * 256 + lane * 4);
  float x2 = wave_sum(x.x * x.x + x.y * x.y + x.z * x.z + x.w * x.w);
  float v2 = wave_sum(v.x * v.x + v.y * v.y + v.z * v.z + v.w * v.w);
  float xv = wave_sum(x.x * v.x + x.y * v.y + x.z * v.z + x.w * v.w);

  float vn = fmaxf(sqrtf(v2), EPS_F);
  float lamx = 2.f / fmaxf(1.f - x2, EPS_F);
  float s = tanhf(0.5f * lamx * vn) / vn;     // second = s * v
  float xy = s * xv;
  float y2 = s * s * v2;
  float a  = 1.f + 2.f * xy + y2;
  float bb = 1.f - x2;
  float den = fmaxf(1.f + 2.f * xy + x2 * y2, EPS_F);
  float inv = 1.f / den;
  float4 res;
  res.x = (a * x.x + bb * s * v.x) * inv;
  res.y = (a * x.y + bb * s * v.y) * inv;
  res.z = (a * x.z + bb * s * v.z) * inv;
  res.w = (a * x.w + bb * s * v.w) * inv;
  float r2 = wave_sum(res.x * res.x + res.y * res.y + res.z * res.z + res.w * res.w);
  float rn = sqrtf(r2);
  if (rn > MAX_NORM_F) {
    float sc = MAX_NORM_F / fmaxf(rn, EPS_F);
    res.x *= sc; res.y *= sc; res.z *= sc; res.w *= sc;
  }
  *reinterpret_cast<float4*>(zr + (size_t)(t + 30) * 256 + lane * 4) = res;
}

// ------------------------------------------------ logmap0 over appended cols
// U[q = r*8 + t] = logmap0(Z[r][30+t])
__global__ __launch_bounds__(256) void logmap0_rows_k(
    const float* __restrict__ Z, float* __restrict__ U)
{
  const int q = blockIdx.x * 4 + (threadIdx.x >> 6);
  const int lane = threadIdx.x & 63;
  const int r = q >> 3;
  const int tt = q & 7;
  float4 z = *reinterpret_cast<const float4*>(Z + ((size_t)r * 38 + 30 + tt) * 256 + lane * 4);
  float z2 = wave_sum(z.x * z.x + z.y * z.y + z.z * z.z + z.w * z.w);
  float nz = fmaxf(sqrtf(z2), EPS_F);
  float c = atanhf(fminf(nz, 1.f - 1e-7f)) / nz;
  float4 o;
  o.x = c * z.x; o.y = c * z.y; o.z = c * z.z; o.w = c * z.w;
  *reinterpret_cast<float4*>(U + (size_t)q * 256 + lane * 4) = o;
}

// ---------------------------------------------------------------- launcher
extern "C" void kernel_launch(void* const* d_in, const int* in_sizes, int n_in,
                              void* d_out, int out_size, void* d_ws, size_t ws_size,
                              hipStream_t stream)
{
  const float* comps[4] = {(const float*)d_in[0], (const float*)d_in[1],
                           (const float*)d_in[2], (const float*)d_in[3]};
  const float* W_embed = (const float*)d_in[4];
  const float* b_embed = (const float*)d_in[5];
  const float* ln_g    = (const float*)d_in[6];
  const float* ln_b    = (const float*)d_in[7];
  const float* W1 = (const float*)d_in[8];
  const float* b1 = (const float*)d_in[9];
  const float* W2 = (const float*)d_in[10];
  const float* b2 = (const float*)d_in[11];
  const float* W3 = (const float*)d_in[12];
  const float* b3 = (const float*)d_in[13];
  const float* W_out = (const float*)d_in[14];
  const float* b_out = (const float*)d_in[15];
  float* out = (float*)d_out;
  float* ws  = (float*)d_ws;

  // ws layout (floats):
  // Z    @ 0           : 2560*38*256 = 24,903,680
  // TAN  @ 24,903,680  : 4*15360*256 = 15,728,640  (dead after ln_expmap0)
  // FEAT @ 24,903,680  : 2560*768    (reuses TAN)
  // H1   @ 26,869,760  : 2560*1024
  // H2   @ 29,491,200  : 2560*1024
  // V    @ 32,112,640  : 2560*256
  // U    @ 24,903,680  : 20480*256   (reuses FEAT after step loop)
  float* Z    = ws;
  float* TAN  = ws + 24903680u;
  float* FEAT = ws + 24903680u;
  float* H1   = ws + 26869760u;
  float* H2   = ws + 29491200u;
  float* V    = ws + 32112640u;
  float* U    = ws + 24903680u;

  dim3 blk(256);

  // Stage A: embedding GEMMs (A rows are contiguous 504-float segments)
  for (int c = 0; c < 4; ++c) {
    gemm_f32<<<dim3(240, 4), blk, 0, stream>>>(
        comps[c], W_embed + (size_t)c * 504 * 256, b_embed + c * 256,
        TAN + (size_t)c * 15360 * 256, 15360, 256, 504, 0);
  }
  ln_expmap0_k<<<dim3(15360), blk, 0, stream>>>(TAN, ln_g, ln_b, Z);

  // Stage B: 8 recurrent steps
  for (int t = 0; t < 8; ++t) {
    vel_feat_k<<<dim3(640), blk, 0, stream>>>(Z, FEAT, t);
    gemm_f32<<<dim3(40, 16), blk, 0, stream>>>(FEAT, W1, b1, H1, 2560, 1024, 768, 1);
    gemm_f32<<<dim3(40, 16), blk, 0, stream>>>(H1, W2, b2, H2, 2560, 1024, 1024, 1);
    gemm_f32<<<dim3(40, 4),  blk, 0, stream>>>(H2, W3, b3, V, 2560, 256, 1024, 0);
    expmap_step_k<<<dim3(640), blk, 0, stream>>>(Z, V, t);
  }

  // Stage C: final projection -> d_out
  logmap0_rows_k<<<dim3(5120), blk, 0, stream>>>(Z, U);
  gemm_f32<<<dim3(320, 8), blk, 0, stream>>>(U, W_out, b_out, out, 20480, 504, 256, 0);
}

// Round 2
// 2208.858 us; speedup vs baseline: 1.2954x; 1.2954x over previous
//
#include <hip/hip_runtime.h>
#include <cstddef>
#include <cstdint>

#define EPS_F 1e-7f
#define MAX_NORM_F 0.99999f   // (1 - 1e-5) / SC, SC = 1

typedef __attribute__((ext_vector_type(8))) short bf16x8;  // 8 bf16 (4 VGPR)
typedef __attribute__((ext_vector_type(4))) float f32x4;

// ---------------------------------------------------------------- helpers
__device__ __forceinline__ unsigned short f2bf(float x) {
  unsigned int u = __float_as_uint(x);
  unsigned int r = u + 0x7FFFu + ((u >> 16) & 1u);   // RNE (no NaN in data)
  return (unsigned short)(r >> 16);
}
__device__ __forceinline__ float bf2f(unsigned short h) {
  return __uint_as_float(((unsigned int)h) << 16);
}

__device__ __forceinline__ float wave_sum(float v) {
#pragma unroll
  for (int off = 32; off; off >>= 1) v += __shfl_xor(v, off);
  return v;
}

__device__ __forceinline__ float block_sum(float v, float* red) {
  const int lane = threadIdx.x & 63;
  const int w = threadIdx.x >> 6;
  v = wave_sum(v);
  __syncthreads();
  if (lane == 0) red[w] = v;
  __syncthreads();
  return red[0] + red[1] + red[2] + red[3];
}

// --------------------------------------------- weight transpose+split pass
// W [K][N] fp32 -> Th/Tl [N][Kp] bf16 (hi, lo), zero-padded for k >= K.
// grid: (ceil(N/64), Kp/64), 256 threads.
__global__ __launch_bounds__(256) void wsplit_k(
    const float* __restrict__ W, unsigned short* __restrict__ Th,
    unsigned short* __restrict__ Tl, int K, int N, int Kp)
{
  __shared__ float T[64][65];
  const int n0 = blockIdx.x * 64, k0 = blockIdx.y * 64;
  const int t = threadIdx.x;
  {
    const int lk = t >> 2;            // 0..63 (k in tile)
    const int ln = (t & 3) * 16;      // n base
    const int gk = k0 + lk;
#pragma unroll
    for (int j = 0; j < 16; j += 4) {
      float4 v = make_float4(0.f, 0.f, 0.f, 0.f);
      const int gn = n0 + ln + j;
      if (gk < K) {
        if (gn + 3 < N) {
          v = *reinterpret_cast<const float4*>(W + (size_t)gk * N + gn);
        } else {
          const float* p = W + (size_t)gk * N;
          if (gn     < N) v.x = p[gn];
          if (gn + 1 < N) v.y = p[gn + 1];
          if (gn + 2 < N) v.z = p[gn + 2];
          if (gn + 3 < N) v.w = p[gn + 3];
        }
      }
      T[lk][ln + j + 0] = v.x; T[lk][ln + j + 1] = v.y;
      T[lk][ln + j + 2] = v.z; T[lk][ln + j + 3] = v.w;
    }
  }
  __syncthreads();
  {
    const int rn = t >> 2;            // n in tile
    const int rk = (t & 3) * 16;      // k base
    const int gn = n0 + rn;
    if (gn < N) {
      size_t base = (size_t)gn * Kp + k0 + rk;
#pragma unroll
      for (int j = 0; j < 16; ++j) {
        float x = T[rk + j][rn];
        unsigned short h = f2bf(x);
        unsigned short l = f2bf(x - bf2f(h));
        Th[base + j] = h;
        Tl[base + j] = l;
      }
    }
  }
}

// --------------------------------------------------------- bf16x3 MFMA GEMM
// C[M,N] = A[M,K](fp32) @ B[K,N] via pre-split BT_h/BT_l [N][Kp] bf16.
// acc += Ah*Bh + Ah*Bl + Al*Bh (fp32 accumulate). 128x128 tile, BK=32,
// 4 waves (2x2), 16x16x32 bf16 MFMA, 4x4 fragments per wave.
// Requires: M % 128 == 0, K % 4 == 0, Kp % 32 == 0 (zero-padded B).
#define LDAB 40   // LDS row stride in bf16 (conflict-free, 16B aligned)

__global__ __launch_bounds__(256) void gemm_x3(
    const float* __restrict__ A, const unsigned short* __restrict__ BTh,
    const unsigned short* __restrict__ BTl, const float* __restrict__ bias,
    float* __restrict__ C, int M, int N, int K, int Kp, int relu)
{
  __shared__ unsigned short sAh[128 * LDAB];
  __shared__ unsigned short sAl[128 * LDAB];
  __shared__ unsigned short sBh[128 * LDAB];
  __shared__ unsigned short sBl[128 * LDAB];

  const int t = threadIdx.x;
  const int bm = blockIdx.x * 128;
  const int bn = blockIdx.y * 128;
  const int lane = t & 63;
  const int wave = t >> 6;
  const int wm = (wave >> 1) * 64;
  const int wn = (wave & 1) * 64;
  const int fr = lane & 15;
  const int kg = lane >> 4;

  // staging mapping: 256 threads cover 128 rows x 32 k (16 els each)
  const int srow = t & 127;
  const int shalf = t >> 7;           // 0/1 -> k-half of 16
  const float* aptr = A + (size_t)(bm + srow) * K + shalf * 16;
  const int brow = bn + srow;
  const bool bval = brow < N;
  const size_t bbase = (size_t)(bval ? brow : 0) * Kp + shalf * 16;
  unsigned short* dAh = &sAh[srow * LDAB + shalf * 16];
  unsigned short* dAl = &sAl[srow * LDAB + shalf * 16];
  unsigned short* dBh = &sBh[srow * LDAB + shalf * 16];
  unsigned short* dBl = &sBl[srow * LDAB + shalf * 16];

  f32x4 acc[4][4] = {};

  for (int k0 = 0; k0 < Kp; k0 += 32) {
    // ---- stage A (fp32 -> split bf16)
    {
      unsigned short ah[16], al[16];
#pragma unroll
      for (int q = 0; q < 4; ++q) {
        const int gk = k0 + shalf * 16 + q * 4;
        float4 v = make_float4(0.f, 0.f, 0.f, 0.f);
        if (gk < K) v = *reinterpret_cast<const float4*>(aptr + k0 + q * 4);
        float xs[4] = {v.x, v.y, v.z, v.w};
#pragma unroll
        for (int i = 0; i < 4; ++i) {
          unsigned short h = f2bf(xs[i]);
          ah[q * 4 + i] = h;
          al[q * 4 + i] = f2bf(xs[i] - bf2f(h));
        }
      }
      bf16x8 p;
#pragma unroll
      for (int i = 0; i < 8; ++i) p[i] = (short)ah[i];
      *reinterpret_cast<bf16x8*>(dAh) = p;
#pragma unroll
      for (int i = 0; i < 8; ++i) p[i] = (short)ah[8 + i];
      *reinterpret_cast<bf16x8*>(dAh + 8) = p;
#pragma unroll
      for (int i = 0; i < 8; ++i) p[i] = (short)al[i];
      *reinterpret_cast<bf16x8*>(dAl) = p;
#pragma unroll
      for (int i = 0; i < 8; ++i) p[i] = (short)al[8 + i];
      *reinterpret_cast<bf16x8*>(dAl + 8) = p;
    }
    // ---- stage B (already split, straight copy)
    {
      int4 z = make_int4(0, 0, 0, 0);
      const int4* ph = reinterpret_cast<const int4*>(BTh + bbase + k0);
      const int4* pl = reinterpret_cast<const int4*>(BTl + bbase + k0);
      int4 h0 = bval ? ph[0] : z;
      int4 h1 = bval ? ph[1] : z;
      int4 l0 = bval ? pl[0] : z;
      int4 l1 = bval ? pl[1] : z;
      reinterpret_cast<int4*>(dBh)[0] = h0;
      reinterpret_cast<int4*>(dBh)[1] = h1;
      reinterpret_cast<int4*>(dBl)[0] = l0;
      reinterpret_cast<int4*>(dBl)[1] = l1;
    }
    __syncthreads();

    // ---- fragments + MFMA
    bf16x8 fah[4], fal[4], fbh[4], fbl[4];
#pragma unroll
    for (int i = 0; i < 4; ++i) {
      const int ar = wm + i * 16 + fr;
      fah[i] = *reinterpret_cast<const bf16x8*>(&sAh[ar * LDAB + kg * 8]);
      fal[i] = *reinterpret_cast<const bf16x8*>(&sAl[ar * LDAB + kg * 8]);
      const int br = wn + i * 16 + fr;
      fbh[i] = *reinterpret_cast<const bf16x8*>(&sBh[br * LDAB + kg * 8]);
      fbl[i] = *reinterpret_cast<const bf16x8*>(&sBl[br * LDAB + kg * 8]);
    }
#pragma unroll
    for (int mi = 0; mi < 4; ++mi)
#pragma unroll
      for (int ni = 0; ni < 4; ++ni) {
        acc[mi][ni] = __builtin_amdgcn_mfma_f32_16x16x32_bf16(
            fah[mi], fbh[ni], acc[mi][ni], 0, 0, 0);
        acc[mi][ni] = __builtin_amdgcn_mfma_f32_16x16x32_bf16(
            fah[mi], fbl[ni], acc[mi][ni], 0, 0, 0);
        acc[mi][ni] = __builtin_amdgcn_mfma_f32_16x16x32_bf16(
            fal[mi], fbh[ni], acc[mi][ni], 0, 0, 0);
      }
    __syncthreads();
  }

  // ---- epilogue: C/D layout col = lane&15, row = (lane>>4)*4 + reg
#pragma unroll
  for (int mi = 0; mi < 4; ++mi) {
#pragma unroll
    for (int ni = 0; ni < 4; ++ni) {
      const int col = bn + wn + ni * 16 + fr;
      if (col >= N) continue;
      const int row = bm + wm + mi * 16 + kg * 4;
      const float bv = bias[col];
#pragma unroll
      for (int r = 0; r < 4; ++r) {
        float v = acc[mi][ni][r] + bv;
        if (relu) v = fmaxf(v, 0.f);
        C[(size_t)(row + r) * N + col] = v;
      }
    }
  }
}

// ------------------------------------------------- LayerNorm + expmap0 -> Z
__global__ __launch_bounds__(256) void ln_expmap0_k(
    const float* __restrict__ TAN, const float* __restrict__ gamma,
    const float* __restrict__ beta, float* __restrict__ Z)
{
  __shared__ float red[4];
  const int row = blockIdx.x;     // b*30 + n
  const int d = threadIdx.x;
  const int b = row / 30;
  const int n = row % 30;

  float tc[4];
  float tsum = 0.f;
#pragma unroll
  for (int c = 0; c < 4; ++c) {
    float x = TAN[((size_t)c * 15360 + row) * 256 + d];
    float mu = block_sum(x, red) * (1.f / 256.f);
    float xm = x - mu;
    float var = block_sum(xm * xm, red) * (1.f / 256.f);
    float tv = xm * rsqrtf(var + 1e-5f) * gamma[c * 256 + d] + beta[c * 256 + d];
    tc[c] = tv;
    tsum += tv;
  }
#pragma unroll
  for (int g = 0; g < 5; ++g) {
    float v = (g == 0) ? tsum : tc[g - 1];
    float n2 = block_sum(v * v, red);
    float nn = fmaxf(sqrtf(n2), EPS_F);
    float th = tanhf(nn);
    float w = v * (th / nn);
    if (th > MAX_NORM_F) w *= MAX_NORM_F / fmaxf(th, EPS_F);
    Z[(((size_t)g * 512 + b) * 38 + n) * 256 + d] = w;
  }
}

// ------------------------------------------------ per-pair logmap (1 wave)
__device__ __forceinline__ float4 pair_log(const float* zr, int c, int lane) {
  float4 x = *reinterpret_cast<const float4*>(zr + (size_t)c * 256 + lane * 4);
  float4 y = *reinterpret_cast<const float4*>(zr + (size_t)(c + 1) * 256 + lane * 4);
  float x2 = wave_sum(x.x * x.x + x.y * x.y + x.z * x.z + x.w * x.w);
  float y2 = wave_sum(y.x * y.x + y.y * y.y + y.z * y.z + y.w * y.w);
  float xy = wave_sum(x.x * y.x + x.y * y.y + x.z * y.z + x.w * y.w);
  float a  = 1.f - 2.f * xy + y2;
  float bb = 1.f - x2;
  float den = fmaxf(1.f - 2.f * xy + x2 * y2, EPS_F);
  float inv = 1.f / den;
  float4 u;
  u.x = (bb * y.x - a * x.x) * inv;
  u.y = (bb * y.y - a * x.y) * inv;
  u.z = (bb * y.z - a * x.z) * inv;
  u.w = (bb * y.w - a * x.w) * inv;
  float u2 = wave_sum(u.x * u.x + u.y * u.y + u.z * u.z + u.w * u.w);
  float un = fmaxf(sqrtf(u2), EPS_F);
  float coef = fmaxf(1.f - x2, EPS_F) * atanhf(fminf(un, 1.f - 1e-7f)) / un;
  float4 o;
  o.x = coef * u.x; o.y = coef * u.y; o.z = coef * u.z; o.w = coef * u.w;
  return o;
}

__device__ __forceinline__ float4 logmap0_col(const float* zr, int c, int lane) {
  float4 z = *reinterpret_cast<const float4*>(zr + (size_t)c * 256 + lane * 4);
  float z2 = wave_sum(z.x * z.x + z.y * z.y + z.z * z.z + z.w * z.w);
  float nz = fmaxf(sqrtf(z2), EPS_F);
  float cc = atanhf(fminf(nz, 1.f - 1e-7f)) / nz;
  float4 o;
  o.x = cc * z.x; o.y = cc * z.y; o.z = cc * z.z; o.w = cc * z.w;
  return o;
}

// -------------------------- velocity (incremental) + feat (per step t)
// VSUM holds sum of 29 pair-logmaps of the current window.
__global__ __launch_bounds__(256) void vel_feat_inc_k(
    const float* __restrict__ Z, float* __restrict__ FEAT,
    float* __restrict__ VSUM, int t)
{
  const int r = blockIdx.x * 4 + (threadIdx.x >> 6);
  const int lane = threadIdx.x & 63;
  const float* zr = Z + (size_t)r * 38 * 256;

  float4 vs;
  if (t == 0) {
    vs = make_float4(0.f, 0.f, 0.f, 0.f);
#pragma unroll 1
    for (int j = 0; j < 29; ++j) {
      float4 p = pair_log(zr, j, lane);
      vs.x += p.x; vs.y += p.y; vs.z += p.z; vs.w += p.w;
    }
  } else {
    vs = *reinterpret_cast<const float4*>(VSUM + (size_t)r * 256 + lane * 4);
    float4 pm = pair_log(zr, t - 1, lane);
    float4 pp = pair_log(zr, t + 28, lane);
    vs.x += pp.x - pm.x; vs.y += pp.y - pm.y;
    vs.z += pp.z - pm.z; vs.w += pp.w - pm.w;
  }
  *reinterpret_cast<float4*>(VSUM + (size_t)r * 256 + lane * 4) = vs;

  float4 fl = logmap0_col(zr, t + 29, lane);   // z_last
  float4 fp = logmap0_col(zr, t + 28, lane);   // z_prev
  float* f = FEAT + (size_t)r * 768;
  *reinterpret_cast<float4*>(f + lane * 4) = fl;
  *reinterpret_cast<float4*>(f + 256 + lane * 4) = fp;
  const float s29 = 1.f / 29.f;
  float4 o;
  o.x = vs.x * s29; o.y = vs.y * s29; o.z = vs.z * s29; o.w = vs.w * s29;
  *reinterpret_cast<float4*>(f + 512 + lane * 4) = o;
}

// ------------------------------------------------ z_next = expmap(z_last, v)
__global__ __launch_bounds__(256) void expmap_step_k(
    float* __restrict__ Z, const float* __restrict__ V, int t)
{
  const int r = blockIdx.x * 4 + (threadIdx.x >> 6);
  const int lane = threadIdx.x & 63;
  float* zr = Z + (size_t)r * 38 * 256;
  float4 x = *reinterpret_cast<const float4*>(zr + (size_t)(t + 29) * 256 + lane * 4);
  float4 v = *reinterpret_cast<const float4*>(V + (size_t)r * 256 + lane * 4);
  float x2 = wave_sum(x.x * x.x + x.y * x.y + x.z * x.z + x.w * x.w);
  float v2 = wave_sum(v.x * v.x + v.y * v.y + v.z * v.z + v.w * v.w);
  float xv = wave_sum(x.x * v.x + x.y * v.y + x.z * v.z + x.w * v.w);

  float vn = fmaxf(sqrtf(v2), EPS_F);
  float lamx = 2.f / fmaxf(1.f - x2, EPS_F);
  float s = tanhf(0.5f * lamx * vn) / vn;
  float xy = s * xv;
  float y2 = s * s * v2;
  float a  = 1.f + 2.f * xy + y2;
  float bb = 1.f - x2;
  float den = fmaxf(1.f + 2.f * xy + x2 * y2, EPS_F);
  float inv = 1.f / den;
  float4 res;
  res.x = (a * x.x + bb * s * v.x) * inv;
  res.y = (a * x.y + bb * s * v.y) * inv;
  res.z = (a * x.z + bb * s * v.z) * inv;
  res.w = (a * x.w + bb * s * v.w) * inv;
  float r2 = wave_sum(res.x * res.x + res.y * res.y + res.z * res.z + res.w * res.w);
  float rn = sqrtf(r2);
  if (rn > MAX_NORM_F) {
    float sc = MAX_NORM_F / fmaxf(rn, EPS_F);
    res.x *= sc; res.y *= sc; res.z *= sc; res.w *= sc;
  }
  *reinterpret_cast<float4*>(zr + (size_t)(t + 30) * 256 + lane * 4) = res;
}

// ------------------------------------------------ logmap0 over appended cols
__global__ __launch_bounds__(256) void logmap0_rows_k(
    const float* __restrict__ Z, float* __restrict__ U)
{
  const int q = blockIdx.x * 4 + (threadIdx.x >> 6);
  const int lane = threadIdx.x & 63;
  const int r = q >> 3;
  const int tt = q & 7;
  float4 o = logmap0_col(Z + (size_t)r * 38 * 256, 30 + tt, lane);
  *reinterpret_cast<float4*>(U + (size_t)q * 256 + lane * 4) = o;
}

// ---------------------------------------------------------------- launcher
extern "C" void kernel_launch(void* const* d_in, const int* in_sizes, int n_in,
                              void* d_out, int out_size, void* d_ws, size_t ws_size,
                              hipStream_t stream)
{
  const float* comps[4] = {(const float*)d_in[0], (const float*)d_in[1],
                           (const float*)d_in[2], (const float*)d_in[3]};
  const float* W_embed = (const float*)d_in[4];
  const float* b_embed = (const float*)d_in[5];
  const float* ln_g    = (const float*)d_in[6];
  const float* ln_b    = (const float*)d_in[7];
  const float* W1 = (const float*)d_in[8];
  const float* b1 = (const float*)d_in[9];
  const float* W2 = (const float*)d_in[10];
  const float* b2 = (const float*)d_in[11];
  const float* W3 = (const float*)d_in[12];
  const float* b3 = (const float*)d_in[13];
  const float* W_out = (const float*)d_in[14];
  const float* b_out = (const float*)d_in[15];
  float* out = (float*)d_out;
  float* ws  = (float*)d_ws;

  // ws layout (float offsets). Peak = Z + TAN = 40,632,320 floats (162.5 MB,
  // proven available in round 1).
  float* Z    = ws;                       // 2560*38*256 = 24,903,680
  float* TAN  = ws + 24903680u;           // 4*15360*256 = 15,728,640 (stage A)
  // After TAN dies: split weights live at the start of the TAN region.
  unsigned short* wu = (unsigned short*)(ws + 24903680u);
  unsigned short* W1h = wu;                        // 1024*768
  unsigned short* W1l = W1h + 786432u;
  unsigned short* W2h = W1l + 786432u;             // 1024*1024
  unsigned short* W2l = W2h + 1048576u;
  unsigned short* W3h = W2l + 1048576u;            // 256*1024
  unsigned short* W3l = W3h + 262144u;
  unsigned short* Woh = W3l + 262144u;             // 504*256
  unsigned short* Wol = Woh + 129024u;             // ends @ float 27,129,856
  float* FEAT = ws + 27262976u;           // 2560*768  -> 29,229,056
  float* H1   = ws + 29229056u;           // 2560*1024 -> 31,850,496
  float* H2   = ws + 31850496u;           // 2560*1024 -> 34,471,936
  float* V    = ws + 34471936u;           // 2560*256  -> 35,127,296
  float* VSUM = ws + 35127296u;           // 2560*256  -> 35,782,656
  float* U    = ws + 27262976u;           // 20480*256 (stage C, reuses FEAT)

  // Embed split weights scratch in d_out (free until final GEMM rewrites it).
  unsigned short* ou = (unsigned short*)d_out;   // 4 * 2*256*512 = 2 MB << out

  dim3 blk(256);

  // -- Pre-pass: split embed weights (K=504 -> Kp=512, N=256)
  for (int c = 0; c < 4; ++c) {
    unsigned short* h = ou + (size_t)c * 262144u;
    wsplit_k<<<dim3(4, 8), blk, 0, stream>>>(
        W_embed + (size_t)c * 504 * 256, h, h + 131072u, 504, 256, 512);
  }

  // -- Stage A: embedding GEMMs (A rows = contiguous 504-float segments)
  for (int c = 0; c < 4; ++c) {
    unsigned short* h = ou + (size_t)c * 262144u;
    gemm_x3<<<dim3(120, 2), blk, 0, stream>>>(
        comps[c], h, h + 131072u, b_embed + c * 256,
        TAN + (size_t)c * 15360 * 256, 15360, 256, 504, 512, 0);
  }
  ln_expmap0_k<<<dim3(15360), blk, 0, stream>>>(TAN, ln_g, ln_b, Z);

  // -- Split MLP + output weights (TAN is dead now)
  wsplit_k<<<dim3(16, 12), blk, 0, stream>>>(W1, W1h, W1l, 768, 1024, 768);
  wsplit_k<<<dim3(16, 16), blk, 0, stream>>>(W2, W2h, W2l, 1024, 1024, 1024);
  wsplit_k<<<dim3(4, 16),  blk, 0, stream>>>(W3, W3h, W3l, 1024, 256, 1024);
  wsplit_k<<<dim3(8, 4),   blk, 0, stream>>>(W_out, Woh, Wol, 256, 504, 256);

  // -- Stage B: 8 recurrent steps
  for (int t = 0; t < 8; ++t) {
    vel_feat_inc_k<<<dim3(640), blk, 0, stream>>>(Z, FEAT, VSUM, t);
    gemm_x3<<<dim3(20, 8), blk, 0, stream>>>(FEAT, W1h, W1l, b1, H1,
                                             2560, 1024, 768, 768, 1);
    gemm_x3<<<dim3(20, 8), blk, 0, stream>>>(H1, W2h, W2l, b2, H2,
                                             2560, 1024, 1024, 1024, 1);
    gemm_x3<<<dim3(20, 2), blk, 0, stream>>>(H2, W3h, W3l, b3, V,
                                             2560, 256, 1024, 1024, 0);
    expmap_step_k<<<dim3(640), blk, 0, stream>>>(Z, V, t);
  }

  // -- Stage C: final projection -> d_out (overwrites embed-weight scratch)
  logmap0_rows_k<<<dim3(5120), blk, 0, stream>>>(Z, U);
  gemm_x3<<<dim3(160, 4), blk, 0, stream>>>(U, Woh, Wol, b_out, out,
                                            20480, 504, 256, 256, 0);
}

// Round 3
// 1053.586 us; speedup vs baseline: 2.7158x; 2.0965x over previous
//
#include <hip/hip_runtime.h>
#include <cstddef>
#include <cstdint>

#define EPS_F 1e-7f
#define MAX_NORM_F 0.99999f   // (1 - 1e-5) / SC, SC = 1

typedef __attribute__((ext_vector_type(8))) short bf16x8;  // 8 bf16 (4 VGPR)
typedef __attribute__((ext_vector_type(4))) float f32x4;

// ---------------------------------------------------------------- helpers
__device__ __forceinline__ unsigned short f2bf(float x) {
  unsigned int u = __float_as_uint(x);
  unsigned int r = u + 0x7FFFu + ((u >> 16) & 1u);   // RNE (no NaN in data)
  return (unsigned short)(r >> 16);
}
__device__ __forceinline__ float bf2f(unsigned short h) {
  return __uint_as_float(((unsigned int)h) << 16);
}

__device__ __forceinline__ float wave_sum(float v) {
#pragma unroll
  for (int off = 32; off; off >>= 1) v += __shfl_xor(v, off);
  return v;
}

__device__ __forceinline__ float block_sum(float v, float* red) {
  const int lane = threadIdx.x & 63;
  const int w = threadIdx.x >> 6;
  v = wave_sum(v);
  __syncthreads();
  if (lane == 0) red[w] = v;
  __syncthreads();
  return red[0] + red[1] + red[2] + red[3];
}

__device__ __forceinline__ void store_split4(unsigned short* H, unsigned short* L,
                                             size_t idx, float4 v) {
  ushort4 h, l;
  h.x = f2bf(v.x); l.x = f2bf(v.x - bf2f(h.x));
  h.y = f2bf(v.y); l.y = f2bf(v.y - bf2f(h.y));
  h.z = f2bf(v.z); l.z = f2bf(v.z - bf2f(h.z));
  h.w = f2bf(v.w); l.w = f2bf(v.w - bf2f(h.w));
  *reinterpret_cast<ushort4*>(H + idx) = h;
  *reinterpret_cast<ushort4*>(L + idx) = l;
}

// --------------------------------------------- weight transpose+split pass
// W [K][N] fp32 -> Th/Tl [N][Kp] bf16 (hi, lo), zero-padded for k >= K.
__global__ __launch_bounds__(256) void wsplit_k(
    const float* __restrict__ W, unsigned short* __restrict__ Th,
    unsigned short* __restrict__ Tl, int K, int N, int Kp)
{
  __shared__ float T[64][65];
  const int n0 = blockIdx.x * 64, k0 = blockIdx.y * 64;
  const int t = threadIdx.x;
  {
    const int lk = t >> 2;
    const int ln = (t & 3) * 16;
    const int gk = k0 + lk;
#pragma unroll
    for (int j = 0; j < 16; j += 4) {
      float4 v = make_float4(0.f, 0.f, 0.f, 0.f);
      const int gn = n0 + ln + j;
      if (gk < K) {
        if (gn + 3 < N) {
          v = *reinterpret_cast<const float4*>(W + (size_t)gk * N + gn);
        } else {
          const float* p = W + (size_t)gk * N;
          if (gn     < N) v.x = p[gn];
          if (gn + 1 < N) v.y = p[gn + 1];
          if (gn + 2 < N) v.z = p[gn + 2];
          if (gn + 3 < N) v.w = p[gn + 3];
        }
      }
      T[lk][ln + j + 0] = v.x; T[lk][ln + j + 1] = v.y;
      T[lk][ln + j + 2] = v.z; T[lk][ln + j + 3] = v.w;
    }
  }
  __syncthreads();
  {
    const int rn = t >> 2;
    const int rk = (t & 3) * 16;
    const int gn = n0 + rn;
    if (gn < N) {
      size_t base = (size_t)gn * Kp + k0 + rk;
#pragma unroll
      for (int j = 0; j < 16; ++j) {
        float x = T[rk + j][rn];
        unsigned short h = f2bf(x);
        unsigned short l = f2bf(x - bf2f(h));
        Th[base + j] = h;
        Tl[base + j] = l;
      }
    }
  }
}

// --------------------------------------------------------- bf16x3 MFMA GEMM
// Shared geometry: 128x128 tile, BK=32, 4 waves (2x2), wave 64x64,
// 16x16x32 bf16 MFMA, acc += Ah*Bh + Ah*Bl + Al*Bh.
#define LDAB 40   // LDS row stride in bf16

#define GEMM_FRAG_MFMA_EPI(biasexpr, reluflag, Cptr, ldcv, Nv)                \
    bf16x8 fah[4], fal[4], fbh[4], fbl[4];                                    \
    _Pragma("unroll")                                                         \
    for (int i = 0; i < 4; ++i) {                                             \
      const int ar = wm + i * 16 + fr;                                        \
      fah[i] = *reinterpret_cast<const bf16x8*>(&sAh[ar * LDAB + kg * 8]);    \
      fal[i] = *reinterpret_cast<const bf16x8*>(&sAl[ar * LDAB + kg * 8]);    \
      const int br = wn + i * 16 + fr;                                        \
      fbh[i] = *reinterpret_cast<const bf16x8*>(&sBh[br * LDAB + kg * 8]);    \
      fbl[i] = *reinterpret_cast<const bf16x8*>(&sBl[br * LDAB + kg * 8]);    \
    }                                                                         \
    _Pragma("unroll")                                                         \
    for (int mi = 0; mi < 4; ++mi)                                            \
      _Pragma("unroll")                                                       \
      for (int ni = 0; ni < 4; ++ni) {                                        \
        acc[mi][ni] = __builtin_amdgcn_mfma_f32_16x16x32_bf16(                \
            fah[mi], fbh[ni], acc[mi][ni], 0, 0, 0);                          \
        acc[mi][ni] = __builtin_amdgcn_mfma_f32_16x16x32_bf16(                \
            fah[mi], fbl[ni], acc[mi][ni], 0, 0, 0);                          \
        acc[mi][ni] = __builtin_amdgcn_mfma_f32_16x16x32_bf16(                \
            fal[mi], fbh[ni], acc[mi][ni], 0, 0, 0);                          \
      }

// ---- variant 1: pre-split A (bf16 hi/lo), partial-K via blockIdx.z
__global__ __launch_bounds__(256) void gemm_x3_pre(
    const unsigned short* __restrict__ Ah, const unsigned short* __restrict__ Al,
    int lda,
    const unsigned short* __restrict__ Bh, const unsigned short* __restrict__ Bl,
    int ldb,
    const float* __restrict__ bias, float* __restrict__ C, int ldc,
    int M, int N, int Ktot, int kslice, int relu)
{
  __shared__ unsigned short sAh[128 * LDAB];
  __shared__ unsigned short sAl[128 * LDAB];
  __shared__ unsigned short sBh[128 * LDAB];
  __shared__ unsigned short sBl[128 * LDAB];

  const int t = threadIdx.x;
  const int bm = blockIdx.x * 128;
  const int bn = blockIdx.y * 128;
  const int z  = blockIdx.z;
  const int koff = z * kslice;
  const int klen = min(kslice, Ktot - koff);
  float* Cz = C + (size_t)z * (size_t)M * (size_t)N;   // z==0 when bias!=null

  const int lane = t & 63, wave = t >> 6;
  const int wm = (wave >> 1) * 64, wn = (wave & 1) * 64;
  const int fr = lane & 15, kg = lane >> 4;

  // staging: thread handles one row, one 32B chunk-pair (2 x bf16x8)
  const int srow = t >> 1, cpair = t & 1;
  const size_t abase = (size_t)(bm + srow) * lda + koff + cpair * 16;
  const int brow = bn + srow;
  const bool bval = brow < N;
  const size_t bbase = (size_t)(bval ? brow : 0) * ldb + koff + cpair * 16;
  const int di = srow * LDAB + cpair * 16;

  f32x4 acc[4][4] = {};

  for (int k0 = 0; k0 < klen; k0 += 32) {
    const int4 z4 = make_int4(0, 0, 0, 0);
    int4 a0 = *reinterpret_cast<const int4*>(Ah + abase + k0);
    int4 a1 = *reinterpret_cast<const int4*>(Ah + abase + k0 + 8);
    int4 a2 = *reinterpret_cast<const int4*>(Al + abase + k0);
    int4 a3 = *reinterpret_cast<const int4*>(Al + abase + k0 + 8);
    int4 b0 = bval ? *reinterpret_cast<const int4*>(Bh + bbase + k0)     : z4;
    int4 b1 = bval ? *reinterpret_cast<const int4*>(Bh + bbase + k0 + 8) : z4;
    int4 b2 = bval ? *reinterpret_cast<const int4*>(Bl + bbase + k0)     : z4;
    int4 b3 = bval ? *reinterpret_cast<const int4*>(Bl + bbase + k0 + 8) : z4;
    *reinterpret_cast<int4*>(sAh + di) = a0;
    *reinterpret_cast<int4*>(sAh + di + 8) = a1;
    *reinterpret_cast<int4*>(sAl + di) = a2;
    *reinterpret_cast<int4*>(sAl + di + 8) = a3;
    *reinterpret_cast<int4*>(sBh + di) = b0;
    *reinterpret_cast<int4*>(sBh + di + 8) = b1;
    *reinterpret_cast<int4*>(sBl + di) = b2;
    *reinterpret_cast<int4*>(sBl + di + 8) = b3;
    __syncthreads();
    GEMM_FRAG_MFMA_EPI(0, 0, 0, 0, 0)
    __syncthreads();
  }

#pragma unroll
  for (int mi = 0; mi < 4; ++mi) {
#pragma unroll
    for (int ni = 0; ni < 4; ++ni) {
      const int col = bn + wn + ni * 16 + fr;
      if (col >= N) continue;
      const int row0 = bm + wm + mi * 16 + kg * 4;
      const float bv = bias ? bias[col] : 0.f;
#pragma unroll
      for (int r = 0; r < 4; ++r) {
        float v = acc[mi][ni][r] + bv;
        if (relu) v = fmaxf(v, 0.f);
        Cz[(size_t)(row0 + r) * ldc + col] = v;
      }
    }
  }
}

// ---- variant 2: embed GEMM, fp32 A (contiguous 504-float segment rows),
// blockIdx.z = component. M=15360, N=256, K=504, Kp=512.
__global__ __launch_bounds__(256) void gemm_x3_embed(
    const float* __restrict__ A0, const float* __restrict__ A1,
    const float* __restrict__ A2, const float* __restrict__ A3,
    const unsigned short* __restrict__ EW, const float* __restrict__ b_embed,
    float* __restrict__ TAN)
{
  __shared__ unsigned short sAh[128 * LDAB];
  __shared__ unsigned short sAl[128 * LDAB];
  __shared__ unsigned short sBh[128 * LDAB];
  __shared__ unsigned short sBl[128 * LDAB];

  const int c = blockIdx.z;
  const float* A = (c == 0) ? A0 : (c == 1) ? A1 : (c == 2) ? A2 : A3;
  const unsigned short* Bh = EW + (size_t)c * 262144u;
  const unsigned short* Bl = Bh + 131072u;
  const float* bias = b_embed + c * 256;
  float* C = TAN + (size_t)c * 15360 * 256;

  const int t = threadIdx.x;
  const int bm = blockIdx.x * 128;
  const int bn = blockIdx.y * 128;
  const int lane = t & 63, wave = t >> 6;
  const int wm = (wave >> 1) * 64, wn = (wave & 1) * 64;
  const int fr = lane & 15, kg = lane >> 4;

  const int srow = t >> 1, cpair = t & 1;
  const float* aptr = A + (size_t)(bm + srow) * 504 + cpair * 16;
  const size_t bbase = (size_t)(bn + srow) * 512 + cpair * 16;
  const int di = srow * LDAB + cpair * 16;

  f32x4 acc[4][4] = {};

  for (int k0 = 0; k0 < 512; k0 += 32) {
    {  // A: fp32 load + split
      unsigned short ah[16], al[16];
#pragma unroll
      for (int q = 0; q < 4; ++q) {
        const int gk = k0 + cpair * 16 + q * 4;
        float4 v = make_float4(0.f, 0.f, 0.f, 0.f);
        if (gk < 504) v = *reinterpret_cast<const float4*>(aptr + k0 + q * 4);
        float xs[4] = {v.x, v.y, v.z, v.w};
#pragma unroll
        for (int i = 0; i < 4; ++i) {
          unsigned short h = f2bf(xs[i]);
          ah[q * 4 + i] = h;
          al[q * 4 + i] = f2bf(xs[i] - bf2f(h));
        }
      }
      bf16x8 p;
#pragma unroll
      for (int i = 0; i < 8; ++i) p[i] = (short)ah[i];
      *reinterpret_cast<bf16x8*>(sAh + di) = p;
#pragma unroll
      for (int i = 0; i < 8; ++i) p[i] = (short)ah[8 + i];
      *reinterpret_cast<bf16x8*>(sAh + di + 8) = p;
#pragma unroll
      for (int i = 0; i < 8; ++i) p[i] = (short)al[i];
      *reinterpret_cast<bf16x8*>(sAl + di) = p;
#pragma unroll
      for (int i = 0; i < 8; ++i) p[i] = (short)al[8 + i];
      *reinterpret_cast<bf16x8*>(sAl + di + 8) = p;
    }
    {  // B: straight copy
      int4 b0 = *reinterpret_cast<const int4*>(Bh + bbase + k0);
      int4 b1 = *reinterpret_cast<const int4*>(Bh + bbase + k0 + 8);
      int4 b2 = *reinterpret_cast<const int4*>(Bl + bbase + k0);
      int4 b3 = *reinterpret_cast<const int4*>(Bl + bbase + k0 + 8);
      *reinterpret_cast<int4*>(sBh + di) = b0;
      *reinterpret_cast<int4*>(sBh + di + 8) = b1;
      *reinterpret_cast<int4*>(sBl + di) = b2;
      *reinterpret_cast<int4*>(sBl + di + 8) = b3;
    }
    __syncthreads();
    GEMM_FRAG_MFMA_EPI(0, 0, 0, 0, 0)
    __syncthreads();
  }

#pragma unroll
  for (int mi = 0; mi < 4; ++mi) {
#pragma unroll
    for (int ni = 0; ni < 4; ++ni) {
      const int col = bn + wn + ni * 16 + fr;   // < 256 always
      const int row0 = bm + wm + mi * 16 + kg * 4;
      const float bv = bias[col];
#pragma unroll
      for (int r = 0; r < 4; ++r)
        C[(size_t)(row0 + r) * 256 + col] = acc[mi][ni][r] + bv;
    }
  }
}

// ------------------------------- fuse: sum split-K parts + bias + relu + split
__global__ __launch_bounds__(256) void fuse_split_k(
    const float* __restrict__ P, int nparts, int partElems,
    const float* __restrict__ bias, int nmask,
    unsigned short* __restrict__ Ch, unsigned short* __restrict__ Cl, int total8)
{
  const int idx = blockIdx.x * 256 + threadIdx.x;
  if (idx >= total8) return;
  const size_t base = (size_t)idx * 8;
  const int col = (int)(base & (size_t)nmask);
  float4 s0 = *reinterpret_cast<const float4*>(P + base);
  float4 s1 = *reinterpret_cast<const float4*>(P + base + 4);
  for (int p = 1; p < nparts; ++p) {
    const float* q = P + (size_t)p * partElems + base;
    float4 a = *reinterpret_cast<const float4*>(q);
    float4 b = *reinterpret_cast<const float4*>(q + 4);
    s0.x += a.x; s0.y += a.y; s0.z += a.z; s0.w += a.w;
    s1.x += b.x; s1.y += b.y; s1.z += b.z; s1.w += b.w;
  }
  float4 bv0 = *reinterpret_cast<const float4*>(bias + col);
  float4 bv1 = *reinterpret_cast<const float4*>(bias + col + 4);
  s0.x = fmaxf(s0.x + bv0.x, 0.f); s0.y = fmaxf(s0.y + bv0.y, 0.f);
  s0.z = fmaxf(s0.z + bv0.z, 0.f); s0.w = fmaxf(s0.w + bv0.w, 0.f);
  s1.x = fmaxf(s1.x + bv1.x, 0.f); s1.y = fmaxf(s1.y + bv1.y, 0.f);
  s1.z = fmaxf(s1.z + bv1.z, 0.f); s1.w = fmaxf(s1.w + bv1.w, 0.f);
  store_split4(Ch, Cl, base, s0);
  store_split4(Ch, Cl, base + 4, s1);
}

// ------------------------------------------------- LayerNorm + expmap0 -> Z
__global__ __launch_bounds__(256) void ln_expmap0_k(
    const float* __restrict__ TAN, const float* __restrict__ gamma,
    const float* __restrict__ beta, float* __restrict__ Z)
{
  __shared__ float red[4];
  const int row = blockIdx.x;     // b*30 + n
  const int d = threadIdx.x;
  const int b = row / 30;
  const int n = row % 30;

  float tc[4];
  float tsum = 0.f;
#pragma unroll
  for (int c = 0; c < 4; ++c) {
    float x = TAN[((size_t)c * 15360 + row) * 256 + d];
    float mu = block_sum(x, red) * (1.f / 256.f);
    float xm = x - mu;
    float var = block_sum(xm * xm, red) * (1.f / 256.f);
    float tv = xm * rsqrtf(var + 1e-5f) * gamma[c * 256 + d] + beta[c * 256 + d];
    tc[c] = tv;
    tsum += tv;
  }
#pragma unroll
  for (int g = 0; g < 5; ++g) {
    float v = (g == 0) ? tsum : tc[g - 1];
    float n2 = block_sum(v * v, red);
    float nn = fmaxf(sqrtf(n2), EPS_F);
    float th = tanhf(nn);
    float w = v * (th / nn);
    if (th > MAX_NORM_F) w *= MAX_NORM_F / fmaxf(th, EPS_F);
    Z[(((size_t)g * 512 + b) * 38 + n) * 256 + d] = w;
  }
}

// ------------------------------------------------ per-pair logmap (1 wave)
__device__ __forceinline__ float4 pair_log(const float* zr, int c, int lane) {
  float4 x = *reinterpret_cast<const float4*>(zr + (size_t)c * 256 + lane * 4);
  float4 y = *reinterpret_cast<const float4*>(zr + (size_t)(c + 1) * 256 + lane * 4);
  float x2 = wave_sum(x.x * x.x + x.y * x.y + x.z * x.z + x.w * x.w);
  float y2 = wave_sum(y.x * y.x + y.y * y.y + y.z * y.z + y.w * y.w);
  float xy = wave_sum(x.x * y.x + x.y * y.y + x.z * y.z + x.w * y.w);
  float a  = 1.f - 2.f * xy + y2;
  float bb = 1.f - x2;
  float den = fmaxf(1.f - 2.f * xy + x2 * y2, EPS_F);
  float inv = 1.f / den;
  float4 u;
  u.x = (bb * y.x - a * x.x) * inv;
  u.y = (bb * y.y - a * x.y) * inv;
  u.z = (bb * y.z - a * x.z) * inv;
  u.w = (bb * y.w - a * x.w) * inv;
  float u2 = wave_sum(u.x * u.x + u.y * u.y + u.z * u.z + u.w * u.w);
  float un = fmaxf(sqrtf(u2), EPS_F);
  float coef = fmaxf(1.f - x2, EPS_F) * atanhf(fminf(un, 1.f - 1e-7f)) / un;
  float4 o;
  o.x = coef * u.x; o.y = coef * u.y; o.z = coef * u.z; o.w = coef * u.w;
  return o;
}

__device__ __forceinline__ float4 logmap0_col(const float* zr, int c, int lane) {
  float4 z = *reinterpret_cast<const float4*>(zr + (size_t)c * 256 + lane * 4);
  float z2 = wave_sum(z.x * z.x + z.y * z.y + z.z * z.z + z.w * z.w);
  float nz = fmaxf(sqrtf(z2), EPS_F);
  float cc = atanhf(fminf(nz, 1.f - 1e-7f)) / nz;
  float4 o;
  o.x = cc * z.x; o.y = cc * z.y; o.z = cc * z.z; o.w = cc * z.w;
  return o;
}

// -------------------------- velocity (incremental) + feat (split bf16 out)
__global__ __launch_bounds__(256) void vel_feat_inc_k(
    const float* __restrict__ Z, unsigned short* __restrict__ Fh,
    unsigned short* __restrict__ Fl, float* __restrict__ VSUM, int t)
{
  const int r = blockIdx.x * 4 + (threadIdx.x >> 6);
  const int lane = threadIdx.x & 63;
  const float* zr = Z + (size_t)r * 38 * 256;

  float4 vs;
  if (t == 0) {
    vs = make_float4(0.f, 0.f, 0.f, 0.f);
#pragma unroll 1
    for (int j = 0; j < 29; ++j) {
      float4 p = pair_log(zr, j, lane);
      vs.x += p.x; vs.y += p.y; vs.z += p.z; vs.w += p.w;
    }
  } else {
    vs = *reinterpret_cast<const float4*>(VSUM + (size_t)r * 256 + lane * 4);
    float4 pm = pair_log(zr, t - 1, lane);
    float4 pp = pair_log(zr, t + 28, lane);
    vs.x += pp.x - pm.x; vs.y += pp.y - pm.y;
    vs.z += pp.z - pm.z; vs.w += pp.w - pm.w;
  }
  *reinterpret_cast<float4*>(VSUM + (size_t)r * 256 + lane * 4) = vs;

  float4 fl = logmap0_col(zr, t + 29, lane);   // z_last
  float4 fp = logmap0_col(zr, t + 28, lane);   // z_prev
  const size_t fb = (size_t)r * 768 + lane * 4;
  store_split4(Fh, Fl, fb, fl);
  store_split4(Fh, Fl, fb + 256, fp);
  const float s29 = 1.f / 29.f;
  float4 o;
  o.x = vs.x * s29; o.y = vs.y * s29; o.z = vs.z * s29; o.w = vs.w * s29;
  store_split4(Fh, Fl, fb + 512, o);
}

// ----------------------- z_next = expmap(z_last, sum(V parts) + b3)
__global__ __launch_bounds__(256) void expmap_step_k(
    float* __restrict__ Z, const float* __restrict__ VP,
    const float* __restrict__ b3, int t)
{
  const int r = blockIdx.x * 4 + (threadIdx.x >> 6);
  const int lane = threadIdx.x & 63;
  float* zr = Z + (size_t)r * 38 * 256;
  float4 x = *reinterpret_cast<const float4*>(zr + (size_t)(t + 29) * 256 + lane * 4);
  float4 v = *reinterpret_cast<const float4*>(b3 + lane * 4);
#pragma unroll
  for (int p = 0; p < 8; ++p) {
    float4 a = *reinterpret_cast<const float4*>(
        VP + (size_t)p * 655360u + (size_t)r * 256 + lane * 4);
    v.x += a.x; v.y += a.y; v.z += a.z; v.w += a.w;
  }
  float x2 = wave_sum(x.x * x.x + x.y * x.y + x.z * x.z + x.w * x.w);
  float v2 = wave_sum(v.x * v.x + v.y * v.y + v.z * v.z + v.w * v.w);
  float xv = wave_sum(x.x * v.x + x.y * v.y + x.z * v.z + x.w * v.w);

  float vn = fmaxf(sqrtf(v2), EPS_F);
  float lamx = 2.f / fmaxf(1.f - x2, EPS_F);
  float s = tanhf(0.5f * lamx * vn) / vn;
  float xy = s * xv;
  float y2 = s * s * v2;
  float a  = 1.f + 2.f * xy + y2;
  float bb = 1.f - x2;
  float den = fmaxf(1.f + 2.f * xy + x2 * y2, EPS_F);
  float inv = 1.f / den;
  float4 res;
  res.x = (a * x.x + bb * s * v.x) * inv;
  res.y = (a * x.y + bb * s * v.y) * inv;
  res.z = (a * x.z + bb * s * v.z) * inv;
  res.w = (a * x.w + bb * s * v.w) * inv;
  float r2 = wave_sum(res.x * res.x + res.y * res.y + res.z * res.z + res.w * res.w);
  float rn = sqrtf(r2);
  if (rn > MAX_NORM_F) {
    float sc = MAX_NORM_F / fmaxf(rn, EPS_F);
    res.x *= sc; res.y *= sc; res.z *= sc; res.w *= sc;
  }
  *reinterpret_cast<float4*>(zr + (size_t)(t + 30) * 256 + lane * 4) = res;
}

// -------------------------- logmap0 over appended cols, split bf16 out
__global__ __launch_bounds__(256) void logmap0_rows_k(
    const float* __restrict__ Z, unsigned short* __restrict__ Uh,
    unsigned short* __restrict__ Ul)
{
  const int q = blockIdx.x * 4 + (threadIdx.x >> 6);
  const int lane = threadIdx.x & 63;
  const int r = q >> 3;
  const int tt = q & 7;
  float4 o = logmap0_col(Z + (size_t)r * 38 * 256, 30 + tt, lane);
  store_split4(Uh, Ul, (size_t)q * 256 + lane * 4, o);
}

// ---------------------------------------------------------------- launcher
extern "C" void kernel_launch(void* const* d_in, const int* in_sizes, int n_in,
                              void* d_out, int out_size, void* d_ws, size_t ws_size,
                              hipStream_t stream)
{
  const float* c0 = (const float*)d_in[0];
  const float* c1 = (const float*)d_in[1];
  const float* c2 = (const float*)d_in[2];
  const float* c3 = (const float*)d_in[3];
  const float* W_embed = (const float*)d_in[4];
  const float* b_embed = (const float*)d_in[5];
  const float* ln_g    = (const float*)d_in[6];
  const float* ln_b    = (const float*)d_in[7];
  const float* W1 = (const float*)d_in[8];
  const float* b1 = (const float*)d_in[9];
  const float* W2 = (const float*)d_in[10];
  const float* b2 = (const float*)d_in[11];
  const float* W3 = (const float*)d_in[12];
  const float* b3 = (const float*)d_in[13];
  const float* W_out = (const float*)d_in[14];
  const float* b_out = (const float*)d_in[15];
  float* out = (float*)d_out;
  float* ws  = (float*)d_ws;

  // ---- ws layout (floats). Peak = Z(24,903,680) + R(15,728,640) = 162.5 MB.
  float* Z = ws;
  float* TAN = ws + 24903680u;                      // R region = TAN in stage A
  unsigned short* Rs = (unsigned short*)(ws + 24903680u);
  unsigned short* W1h = Rs;                         // [1024][768]
  unsigned short* W1l = Rs + 786432u;
  unsigned short* W2h = Rs + 1572864u;              // [1024][1024]
  unsigned short* W2l = Rs + 2621440u;
  unsigned short* W3h = Rs + 3670016u;              // [256][1024]
  unsigned short* W3l = Rs + 3932160u;
  unsigned short* Woh = Rs + 4194304u;              // [504][256]
  unsigned short* Wol = Rs + 4323328u;
  unsigned short* FEATh = Rs + 4452352u;            // [2560][768]
  unsigned short* FEATl = Rs + 6418432u;
  unsigned short* H1h = Rs + 8384512u;              // [2560][1024]
  unsigned short* H1l = Rs + 11005952u;
  unsigned short* H2h = Rs + 13627392u;             // [2560][1024]
  unsigned short* H2l = Rs + 16248832u;             // ends @ short 18,870,272
  float* VP   = ws + 34338816u;                     // 8 x 2560*256 parts
  float* VSUM = ws + 39581696u;                     // 2560*256
  unsigned short* Uh = Rs + 4452352u;               // stage C, reuses FEAT/H1
  unsigned short* Ul = Rs + 9695232u;

  // ---- d_out scratch: embed weights (stage A), split-K partials (stage B).
  unsigned short* EW = (unsigned short*)d_out;      // 4 x (h 131072 | l 131072)
  float* P = (float*)d_out;                         // 3 x 2560*1024 partials

  dim3 blk(256);

  // Stage A: embed weight split -> embed GEMM (z-fused) -> LN+expmap0
  for (int c = 0; c < 4; ++c) {
    unsigned short* h = EW + (size_t)c * 262144u;
    wsplit_k<<<dim3(4, 8), blk, 0, stream>>>(
        W_embed + (size_t)c * 504 * 256, h, h + 131072u, 504, 256, 512);
  }
  gemm_x3_embed<<<dim3(120, 2, 4), blk, 0, stream>>>(
      c0, c1, c2, c3, EW, b_embed, TAN);
  ln_expmap0_k<<<dim3(15360), blk, 0, stream>>>(TAN, ln_g, ln_b, Z);

  // MLP/out weight splits (TAN dead now)
  wsplit_k<<<dim3(16, 12), blk, 0, stream>>>(W1, W1h, W1l, 768, 1024, 768);
  wsplit_k<<<dim3(16, 16), blk, 0, stream>>>(W2, W2h, W2l, 1024, 1024, 1024);
  wsplit_k<<<dim3(4, 16),  blk, 0, stream>>>(W3, W3h, W3l, 1024, 256, 1024);
  wsplit_k<<<dim3(8, 4),   blk, 0, stream>>>(W_out, Woh, Wol, 256, 504, 256);

  // Stage B: 8 recurrent steps
  for (int t = 0; t < 8; ++t) {
    vel_feat_inc_k<<<dim3(640), blk, 0, stream>>>(Z, FEATh, FEATl, VSUM, t);
    gemm_x3_pre<<<dim3(20, 8, 3), blk, 0, stream>>>(
        FEATh, FEATl, 768, W1h, W1l, 768, nullptr, P, 1024,
        2560, 1024, 768, 256, 0);
    fuse_split_k<<<dim3(1280), blk, 0, stream>>>(
        P, 3, 2621440, b1, 1023, H1h, H1l, 327680);
    gemm_x3_pre<<<dim3(20, 8, 3), blk, 0, stream>>>(
        H1h, H1l, 1024, W2h, W2l, 1024, nullptr, P, 1024,
        2560, 1024, 1024, 352, 0);
    fuse_split_k<<<dim3(1280), blk, 0, stream>>>(
        P, 3, 2621440, b2, 1023, H2h, H2l, 327680);
    gemm_x3_pre<<<dim3(20, 2, 8), blk, 0, stream>>>(
        H2h, H2l, 1024, W3h, W3l, 1024, nullptr, VP, 256,
        2560, 256, 1024, 128, 0);
    expmap_step_k<<<dim3(640), blk, 0, stream>>>(Z, VP, b3, t);
  }

  // Stage C: logmap0 -> final projection into d_out
  logmap0_rows_k<<<dim3(5120), blk, 0, stream>>>(Z, Uh, Ul);
  gemm_x3_pre<<<dim3(160, 4, 1), blk, 0, stream>>>(
      Uh, Ul, 256, Woh, Wol, 256, b_out, out, 504,
      20480, 504, 256, 256, 0);
}